// Round 7
// baseline (541467.578 us; speedup 1.0000x reference)
//
#include <hip/hip_runtime.h>
#include <cstdint>
#include <cstddef>

// ============================================================================
// LSTM forecaster, MI355X — R7: same-XCD L2 exchange, L1-proof consumer path.
// R6 post-mortem: census/roles work (numeric s_getreg XCC_ID balanced, FAST
// path ran); failure was sc0 global_load polls hitting stale L1 (sc0 is the
// atomic return-old bit, not an L1 bypass). R7: consumers poll with
// workgroup-scope atomic fetch_add(0) — all global atomics execute at the TCC
// (L2), never L1 -> same-XCD dirty lines are seen. Producers: plain volatile
// store (write-through L1 -> local L2) + agent-scope MALL mirror (safety).
// Bounded spin -> agent loads = final escape hatch; no semantic world hangs.
// Gate math spread across all 1024 threads (shfl-packed 8B publish).
// ============================================================================

typedef __bf16 bf16x8 __attribute__((ext_vector_type(8)));
typedef float  f32x4  __attribute__((ext_vector_type(4)));

static constexpr unsigned long long SENT = 0x7FC07FC07FC07FC0ULL;  // 4x bf16 NaN

// ---- workspace layout (bytes) ----
static constexpr size_t SZ_HALL = (size_t)705 * 128 * 512 * 2;  // h slots 0..704
static constexpr size_t SZ_WCAT = (size_t)2048 * 576 * 2;       // [Whh | Wfuse] bf16
static constexpr size_t SZ_WIH  = (size_t)2048 * 512 * 2;       // Wih bf16 (AR phase)
static constexpr size_t SZ_DECW = (size_t)64 * 512 * 2;         // dec_W bf16
static constexpr size_t SZ_XT   = (size_t)512 * 128 * 64 * 2;   // x transposed [t][b][c]
static constexpr size_t OFF_HALL = 0;
static constexpr size_t OFF_WCAT = OFF_HALL + SZ_HALL;
static constexpr size_t OFF_WIH  = OFF_WCAT + SZ_WCAT;
static constexpr size_t OFF_DECW = OFF_WIH + SZ_WIH;
static constexpr size_t OFF_XT   = OFF_DECW + SZ_DECW;
static constexpr size_t OFF_B2   = OFF_XT + SZ_XT;              // 2048 f32
static constexpr size_t OFF_BAR_ = OFF_B2 + 2048 * 4;           // b_ar 2048 f32
static constexpr size_t OFF_CENS = OFF_BAR_ + 2048 * 4;         // census 64 u32
static constexpr size_t WS_NEEDED = OFF_CENS + 256;

__device__ __forceinline__ float sigm(float x) { return 1.f / (1.f + __expf(-x)); }
__device__ __forceinline__ float tanh_fast(float x) {
  return 1.f - 2.f / (__expf(2.f * x) + 1.f);  // correct +/-1 limits
}

// ---------------------------------------------------------------------------
// setup0: conversions + h slot0 zeros + sentinel fill + census reset.
// ---------------------------------------------------------------------------
__global__ void __launch_bounds__(256)
setup0(const float* __restrict__ x, const float* __restrict__ Wih,
       const float* __restrict__ Whh, const float* __restrict__ bih,
       const float* __restrict__ bhh, const float* __restrict__ decW,
       __bf16* __restrict__ xT, __bf16* __restrict__ Wih_bf,
       __bf16* __restrict__ Wcat, __bf16* __restrict__ decW_bf,
       float* __restrict__ b_ar, __bf16* __restrict__ h_all,
       unsigned* __restrict__ census)
{
  size_t gid = (size_t)blockIdx.x * blockDim.x + threadIdx.x;
  size_t gsz = (size_t)gridDim.x * blockDim.x;
  for (size_t i = gid; i < 4194304u; i += gsz) {          // xT[t][b][c] = x[b][t][c]
    size_t t = i >> 13, b = (i >> 6) & 127u, c = i & 63u;
    xT[i] = (__bf16)x[(b * 512 + t) * 64 + c];
  }
  for (size_t i = gid; i < 1048576u; i += gsz) Wih_bf[i] = (__bf16)Wih[i];
  for (size_t i = gid; i < 1048576u; i += gsz) {
    size_t r = i >> 9, k = i & 511u;
    Wcat[r * 576 + k] = (__bf16)Whh[i];                   // cols 0..511 = Whh
  }
  for (size_t i = gid; i < 32768u; i += gsz) decW_bf[i] = (__bf16)decW[i];
  for (size_t i = gid; i < 2048u; i += gsz) b_ar[i] = bih[i] + bhh[i];
  unsigned long long* hp = (unsigned long long*)h_all;
  for (size_t i = gid; i < 16384u; i += gsz) hp[i] = 0ULL;               // slot 0 = 0
  for (size_t i = 16384u + gid; i < 11550720u; i += gsz) hp[i] = SENT;   // slots 1..704
  for (size_t i = gid; i < 64u; i += gsz) census[i] = 0xFFFFFFFFu;
}

// ---------------------------------------------------------------------------
// setup1: Wfuse = Wih @ enc_W -> Wcat cols 512..575 ; b2 = bih+bhh+Wih@enc_b
// ---------------------------------------------------------------------------
__global__ void __launch_bounds__(64)
setup1(const float* __restrict__ Wih, const float* __restrict__ encW,
       const float* __restrict__ encb, const float* __restrict__ bih,
       const float* __restrict__ bhh, __bf16* __restrict__ Wcat,
       float* __restrict__ b2)
{
  int r = blockIdx.x;        // 0..2047
  int c = threadIdx.x;       // 0..63
  const float* wr = Wih + (size_t)r * 512;
  float acc = 0.f;
  for (int k = 0; k < 512; ++k) acc += wr[k] * encW[(size_t)k * 64 + c];
  Wcat[(size_t)r * 576 + 512 + c] = (__bf16)acc;
  float p = 0.f;
  for (int kk = 0; kk < 8; ++kk) { int k = kk * 64 + c; p += wr[k] * encb[k]; }
  for (int off = 32; off > 0; off >>= 1) p += __shfl_down(p, off);
  if (c == 0) b2[r] = bih[r] + bhh[r] + p;
}

// ---------------------------------------------------------------------------
// One LSTM step. block = 1024 thr (16 waves). MFMA wave wv: gate=wv&3,
// fsub=wv>>2. Gate math: all threads, em=tid>>6 (batch), ef=tid&63 (feature).
// ---------------------------------------------------------------------------
template<bool MAIN, bool FAST>
__device__ __forceinline__ void lstm_step(
    unsigned t, int tid, int wv, int lane, int b0, int f0,
    const bf16x8 (&wf)[18], float bv,
    __bf16* __restrict__ h_all, const __bf16* __restrict__ xT,
    float& creg, __bf16 (*A)[584], float (*ex)[64][17])
{
  const int n16 = lane & 15, quad = lane >> 4;
  const int gate = wv & 3, fsub = wv >> 2;

  // ---- x prefetch (plain cached load; immutable data) ----
  uint4 xv;
  if (MAIN && tid < 128)
    xv = *(const uint4*)(xT + (size_t)(t - 1) * 8192 +
                         (size_t)(b0 + (tid >> 3)) * 64 + (tid & 7) * 8);

  // ---- poll h_{t-1}: 2 x 8B pieces per thread ----
  unsigned long long* src = (unsigned long long*)
      (h_all + (size_t)(t - 1) * 65536 + (size_t)(b0 + (tid >> 6)) * 512) +
      (size_t)(tid & 63) * 2;
  unsigned long long v0, v1;
  if (FAST) {
    // atomic RMW executes at the TCC (L2) — structurally bypasses L1.
    v0 = __hip_atomic_fetch_add(src,     0ULL, __ATOMIC_RELAXED, __HIP_MEMORY_SCOPE_WORKGROUP);
    v1 = __hip_atomic_fetch_add(src + 1, 0ULL, __ATOMIC_RELAXED, __HIP_MEMORY_SCOPE_WORKGROUP);
    int spins = 0;
    while (v0 == SENT || v1 == SENT) {
      if (++spins < 4096) {
        if (v0 == SENT) v0 = __hip_atomic_fetch_add(src,     0ULL, __ATOMIC_RELAXED, __HIP_MEMORY_SCOPE_WORKGROUP);
        if (v1 == SENT) v1 = __hip_atomic_fetch_add(src + 1, 0ULL, __ATOMIC_RELAXED, __HIP_MEMORY_SCOPE_WORKGROUP);
      } else {  // escape hatch: MALL mirror is guaranteed visible
        if (v0 == SENT) v0 = __hip_atomic_load(src,     __ATOMIC_RELAXED, __HIP_MEMORY_SCOPE_AGENT);
        if (v1 == SENT) v1 = __hip_atomic_load(src + 1, __ATOMIC_RELAXED, __HIP_MEMORY_SCOPE_AGENT);
      }
    }
  } else {
    v0 = __hip_atomic_load(src,     __ATOMIC_RELAXED, __HIP_MEMORY_SCOPE_AGENT);
    v1 = __hip_atomic_load(src + 1, __ATOMIC_RELAXED, __HIP_MEMORY_SCOPE_AGENT);
    while (v0 == SENT || v1 == SENT) {
      if (v0 == SENT) v0 = __hip_atomic_load(src,     __ATOMIC_RELAXED, __HIP_MEMORY_SCOPE_AGENT);
      if (v1 == SENT) v1 = __hip_atomic_load(src + 1, __ATOMIC_RELAXED, __HIP_MEMORY_SCOPE_AGENT);
    }
  }

  // ---- stage A (data already in registers) ----
  {
    unsigned long long* ad = (unsigned long long*)&A[tid >> 6][(tid & 63) * 8];
    ad[0] = v0; ad[1] = v1;
  }
  if (MAIN && tid < 128)
    *(uint4*)(&A[tid >> 3][512 + (tid & 7) * 8]) = xv;
  __syncthreads();

  // ---- MFMA: wave (gate, fsub); bias pre-loaded into accumulator ----
  if (MAIN || gate != 1) {
    f32x4 a0 = {bv, bv, bv, bv}, a1 = {0.f, 0.f, 0.f, 0.f};
    const __bf16* arow = &A[n16][quad * 8];
    #pragma unroll
    for (int kc = 0; kc < (MAIN ? 18 : 16); ++kc) {
      bf16x8 af = *(const bf16x8*)(arow + kc * 32);
      if (kc & 1) a1 = __builtin_amdgcn_mfma_f32_16x16x32_bf16(af, wf[kc], a1, 0, 0, 0);
      else        a0 = __builtin_amdgcn_mfma_f32_16x16x32_bf16(af, wf[kc], a0, 0, 0, 0);
    }
    a0 += a1;
    #pragma unroll
    for (int r = 0; r < 4; ++r)
      ex[gate][fsub * 16 + n16][quad * 4 + r] = a0[r];   // [gate][feat 0..63][batch]
  }
  __syncthreads();

  // ---- gates on ALL 1024 threads: em = wave = batch, ef = lane = feature ----
  {
    const int em = tid >> 6, ef = tid & 63;
    float ig = sigm(ex[0][ef][em]);
    float gg = tanh_fast(ex[2][ef][em]);
    float og = sigm(ex[3][ef][em]);
    float c2;
    if (MAIN) { float fg = sigm(ex[1][ef][em]); c2 = fg * creg + ig * gg; creg = c2; }
    else      { c2 = ig * gg; }               // AR: zero state
    float h2 = og * tanh_fast(c2);
    unsigned hv = (unsigned)__builtin_bit_cast(unsigned short, (__bf16)h2);
    // pack 4 lanes' bf16 into one 8B piece on lanes ef%4==0
    unsigned u32v = hv | (((unsigned)__shfl_down((int)hv, 1)) << 16);
    unsigned long long pk = (unsigned long long)u32v |
        ((unsigned long long)(unsigned)__shfl_down((int)u32v, 2) << 32);
    if ((ef & 3) == 0) {
      unsigned long long* dst = (unsigned long long*)
          (h_all + (size_t)t * 65536 + (size_t)(b0 + em) * 512 + f0) + (ef >> 2);
      if (FAST) {
        *(volatile unsigned long long*)dst = pk;  // write-through L1 -> local L2
        __hip_atomic_store(dst, pk, __ATOMIC_RELAXED, __HIP_MEMORY_SCOPE_AGENT);  // MALL mirror
      } else {
        __hip_atomic_store(dst, pk, __ATOMIC_RELAXED, __HIP_MEMORY_SCOPE_AGENT);
      }
    }
  }
}

template<bool FAST>
__device__ __forceinline__ void run_lstm(
    int tid, int wv, int lane, int b0, int f0,
    const __bf16* __restrict__ Wcat, const __bf16* __restrict__ Wih_bf,
    const float* __restrict__ b2, const float* __restrict__ b_ar,
    __bf16* __restrict__ h_all, const __bf16* __restrict__ xT,
    __bf16 (*A)[584], float (*ex)[64][17])
{
  const int n16 = lane & 15, quad = lane >> 4;
  const int gate = wv & 3, fsub = wv >> 2;

  bf16x8 wf[18];
  {
    const __bf16* wrow = Wcat + (size_t)(gate * 512 + f0 + fsub * 16 + n16) * 576 + quad * 8;
    #pragma unroll
    for (int kc = 0; kc < 18; ++kc) wf[kc] = *(const bf16x8*)(wrow + kc * 32);
  }
  float bvm = b2[gate * 512 + f0 + fsub * 16 + n16];
  float creg = 0.f;   // cell state c[b0 + tid>>6][f0 + (tid&63)]

  for (unsigned t = 1; t <= 512; ++t)
    lstm_step<true, FAST>(t, tid, wv, lane, b0, f0, wf, bvm, h_all, xT, creg, A, ex);

  { // AR phase: h feeds Wih with zero recurrent state
    const __bf16* wrow = Wih_bf + (size_t)(gate * 512 + f0 + fsub * 16 + n16) * 512 + quad * 8;
    #pragma unroll
    for (int kc = 0; kc < 16; ++kc) wf[kc] = *(const bf16x8*)(wrow + kc * 32);
  }
  float bva = b_ar[gate * 512 + f0 + fsub * 16 + n16];
  for (unsigned t = 513; t <= 704; ++t)
    lstm_step<false, FAST>(t, tid, wv, lane, b0, f0, wf, bva, h_all, xT, creg, A, ex);
}

__global__ void __launch_bounds__(1024, 4)
lstm_persist(const __bf16* __restrict__ xT, const __bf16* __restrict__ Wcat,
             const __bf16* __restrict__ Wih_bf, const float* __restrict__ b2,
             const float* __restrict__ b_ar, __bf16* __restrict__ h_all,
             unsigned* __restrict__ census)
{
  const int bid = blockIdx.x;                  // 64 blocks
  const int tid = threadIdx.x;
  const int wv = tid >> 6, lane = tid & 63;

  __shared__ __align__(16) __bf16 A[16][584];
  __shared__ float ex[4][64][17];
  __shared__ int censL[64];

  // ---- XCD census (numeric enc: id=20, offset=0, size=8 -> 20 | (7<<11)).
  //      R6 evidence: returns balanced 8x8 -> genuine XCC_ID. ----
  unsigned xcc = __builtin_amdgcn_s_getreg(20 | (7 << 11)) & 0xFFu;
  if (tid == 0)
    __hip_atomic_store(&census[bid], xcc, __ATOMIC_RELAXED, __HIP_MEMORY_SCOPE_SYSTEM);
  if (tid < 64) {
    unsigned vv;
    while ((vv = __hip_atomic_load(&census[tid], __ATOMIC_RELAXED,
                                   __HIP_MEMORY_SCOPE_SYSTEM)) == 0xFFFFFFFFu)
      __builtin_amdgcn_s_sleep(1);
    censL[tid] = (int)vv;
  }
  __syncthreads();

  // ---- role assignment (deterministic from census; all blocks agree) ----
  int cnt[8] = {0, 0, 0, 0, 0, 0, 0, 0};
  const int myx = censL[bid];
  bool bal = true;
  int rank = 0;
  for (int j = 0; j < 64; ++j) {
    int c = censL[j];
    if ((unsigned)c > 7u) { bal = false; break; }
    cnt[c]++;
    if (j < bid && c == myx) rank++;
  }
  if (bal)
    for (int i = 0; i < 8; ++i) bal = bal && (cnt[i] == 8);

  int grp, sub;
  if (bal) { grp = myx;     sub = rank;     }   // group == XCD -> L2-local comm
  else     { grp = bid & 7; sub = bid >> 3; }   // fallback: R4 roles + agent scope
  const int b0 = grp * 16, f0 = sub * 64;

  if (bal)
    run_lstm<true >(tid, wv, lane, b0, f0, Wcat, Wih_bf, b2, b_ar, h_all, xT, A, ex);
  else
    run_lstm<false>(tid, wv, lane, b0, f0, Wcat, Wih_bf, b2, b_ar, h_all, xT, A, ex);
}

// ---------------------------------------------------------------------------
// final_proj: out[b][j][c] = h_slot[j+2][b][:] @ dec_W.T + dec_b, j=0..702.
// (kernel-end release of lstm_persist flushes dirty L2 h lines.)
// ---------------------------------------------------------------------------
__global__ void __launch_bounds__(256)
final_proj(const __bf16* __restrict__ h_all, const __bf16* __restrict__ decW_bf,
           const float* __restrict__ decb, float* __restrict__ out)
{
  const int bi = blockIdx.x;               // 0..702
  const int tid = threadIdx.x;
  const int wv = tid >> 6, lane = tid & 63;
  const int n16 = lane & 15, quad = lane >> 4;
  const size_t r0 = 256 + (size_t)bi * 128 + (size_t)wv * 32;

  f32x4 acc[2][4];
  #pragma unroll
  for (int mt = 0; mt < 2; ++mt)
    #pragma unroll
    for (int nt = 0; nt < 4; ++nt) acc[mt][nt] = f32x4{0.f, 0.f, 0.f, 0.f};

  const __bf16* arow0 = h_all + (r0 + n16) * 512 + quad * 8;
  const __bf16* arow1 = arow0 + 16 * 512;
  const __bf16* brow  = decW_bf + (size_t)n16 * 512 + quad * 8;

  #pragma unroll
  for (int kc = 0; kc < 16; ++kc) {
    bf16x8 a0 = *(const bf16x8*)(arow0 + kc * 32);
    bf16x8 a1 = *(const bf16x8*)(arow1 + kc * 32);
    #pragma unroll
    for (int nt = 0; nt < 4; ++nt) {
      bf16x8 b = *(const bf16x8*)(brow + (size_t)nt * 8192 + kc * 32);
      acc[0][nt] = __builtin_amdgcn_mfma_f32_16x16x32_bf16(a0, b, acc[0][nt], 0, 0, 0);
      acc[1][nt] = __builtin_amdgcn_mfma_f32_16x16x32_bf16(a1, b, acc[1][nt], 0, 0, 0);
    }
  }
  #pragma unroll
  for (int mt = 0; mt < 2; ++mt)
    #pragma unroll
    for (int nt = 0; nt < 4; ++nt)
      #pragma unroll
      for (int r = 0; r < 4; ++r) {
        size_t R = r0 + mt * 16 + quad * 4 + r;      // h_all row
        int slot = (int)(R >> 7), b = (int)(R & 127);
        int j = slot - 2;
        int c = nt * 16 + n16;
        out[((size_t)b * 703 + j) * 64 + c] = acc[mt][nt][r] + decb[c];
      }
}

// ---------------------------------------------------------------------------
extern "C" void kernel_launch(void* const* d_in, const int* in_sizes, int n_in,
                              void* d_out, int out_size, void* d_ws, size_t ws_size,
                              hipStream_t stream)
{
  const float* x    = (const float*)d_in[0];
  const float* encW = (const float*)d_in[1];
  const float* encb = (const float*)d_in[2];
  const float* Wih  = (const float*)d_in[3];
  const float* Whh  = (const float*)d_in[4];
  const float* bih  = (const float*)d_in[5];
  const float* bhh  = (const float*)d_in[6];
  const float* decW = (const float*)d_in[7];
  const float* decb = (const float*)d_in[8];
  float* out = (float*)d_out;

  if (ws_size < WS_NEEDED) return;

  char* ws = (char*)d_ws;
  __bf16*   h_all   = (__bf16*)(ws + OFF_HALL);
  __bf16*   Wcat    = (__bf16*)(ws + OFF_WCAT);
  __bf16*   Wih_bf  = (__bf16*)(ws + OFF_WIH);
  __bf16*   decW_bf = (__bf16*)(ws + OFF_DECW);
  __bf16*   xT      = (__bf16*)(ws + OFF_XT);
  float*    b2      = (float*)(ws + OFF_B2);
  float*    b_ar    = (float*)(ws + OFF_BAR_);
  unsigned* census  = (unsigned*)(ws + OFF_CENS);

  hipLaunchKernelGGL(setup0, dim3(2048), dim3(256), 0, stream,
                     x, Wih, Whh, bih, bhh, decW, xT, Wih_bf, Wcat, decW_bf,
                     b_ar, h_all, census);
  hipLaunchKernelGGL(setup1, dim3(2048), dim3(64), 0, stream,
                     Wih, encW, encb, bih, bhh, Wcat, b2);
  hipLaunchKernelGGL(lstm_persist, dim3(64), dim3(1024), 0, stream,
                     xT, Wcat, Wih_bf, b2, b_ar, h_all, census);
  hipLaunchKernelGGL(final_proj, dim3(703), dim3(256), 0, stream,
                     h_all, decW_bf, decb, out);
}

// Round 8
// 2617.508 us; speedup vs baseline: 206.8638x; 206.8638x over previous
//
#include <hip/hip_runtime.h>
#include <cstdint>
#include <cstddef>

// ============================================================================
// LSTM forecaster, MI355X — R8: flag-based rendezvous over the MALL.
// R6/R7 post-mortem: both L1-bypass and L2-atomic-RMW polls see stale lines
// forever while agent loads see data instantly => producer/consumer L2s are
// NOT co-located (census XCD-grouping premise false). Intra-XCD L2 comm is
// abandoned; all communication uses the PROVEN agent-scope/MALL ops (R2/R4).
// R8 restructures R4's sentinel polling into a generation-flag protocol:
//   producer: h stores (agent) -> s_waitcnt vmcnt(0) per gate wave ->
//             __syncthreads -> flag[g][sub] = t (relaxed agent).
//   consumer: poll ONE 8B flag (its piece's producer) -> issue 2 data loads
//             ONCE (agent). MALL serializes: flag=t implies data readable.
// No sentinel prefill, no fences, no escape hatches needed (flags monotonic,
// agent ops proven fresh). Detection quantization ~halved, poll traffic /128.
// ============================================================================

typedef __bf16 bf16x8 __attribute__((ext_vector_type(8)));
typedef float  f32x4  __attribute__((ext_vector_type(4)));

// ---- workspace layout (bytes) ----
static constexpr size_t SZ_HALL = (size_t)705 * 128 * 512 * 2;  // h slots 0..704
static constexpr size_t SZ_WCAT = (size_t)2048 * 576 * 2;       // [Whh | Wfuse] bf16
static constexpr size_t SZ_WIH  = (size_t)2048 * 512 * 2;       // Wih bf16 (AR phase)
static constexpr size_t SZ_DECW = (size_t)64 * 512 * 2;         // dec_W bf16
static constexpr size_t SZ_XT   = (size_t)512 * 128 * 64 * 2;   // x transposed [t][b][c]
static constexpr size_t OFF_HALL = 0;
static constexpr size_t OFF_WCAT = OFF_HALL + SZ_HALL;
static constexpr size_t OFF_WIH  = OFF_WCAT + SZ_WCAT;
static constexpr size_t OFF_DECW = OFF_WIH + SZ_WIH;
static constexpr size_t OFF_XT   = OFF_DECW + SZ_DECW;
static constexpr size_t OFF_B2   = OFF_XT + SZ_XT;              // 2048 f32
static constexpr size_t OFF_BAR_ = OFF_B2 + 2048 * 4;           // b_ar 2048 f32
static constexpr size_t OFF_FLAG = OFF_BAR_ + 2048 * 4;         // 64 flags, 64B stride
static constexpr size_t WS_NEEDED = OFF_FLAG + 4096;

__device__ __forceinline__ float sigm(float x) { return 1.f / (1.f + __expf(-x)); }
__device__ __forceinline__ float tanh_fast(float x) {
  return 1.f - 2.f / (__expf(2.f * x) + 1.f);  // correct +/-1 limits
}

// ---------------------------------------------------------------------------
// setup0: conversions + h slot0 zeros + flag reset. (No sentinel fill: the
// flag protocol guarantees values; slots 1..704 may stay poisoned until
// their producing step.)
// ---------------------------------------------------------------------------
__global__ void __launch_bounds__(256)
setup0(const float* __restrict__ x, const float* __restrict__ Wih,
       const float* __restrict__ Whh, const float* __restrict__ bih,
       const float* __restrict__ bhh, const float* __restrict__ decW,
       __bf16* __restrict__ xT, __bf16* __restrict__ Wih_bf,
       __bf16* __restrict__ Wcat, __bf16* __restrict__ decW_bf,
       float* __restrict__ b_ar, __bf16* __restrict__ h_all,
       unsigned long long* __restrict__ flags)
{
  size_t gid = (size_t)blockIdx.x * blockDim.x + threadIdx.x;
  size_t gsz = (size_t)gridDim.x * blockDim.x;
  for (size_t i = gid; i < 4194304u; i += gsz) {          // xT[t][b][c] = x[b][t][c]
    size_t t = i >> 13, b = (i >> 6) & 127u, c = i & 63u;
    xT[i] = (__bf16)x[(b * 512 + t) * 64 + c];
  }
  for (size_t i = gid; i < 1048576u; i += gsz) Wih_bf[i] = (__bf16)Wih[i];
  for (size_t i = gid; i < 1048576u; i += gsz) {
    size_t r = i >> 9, k = i & 511u;
    Wcat[r * 576 + k] = (__bf16)Whh[i];                   // cols 0..511 = Whh
  }
  for (size_t i = gid; i < 32768u; i += gsz) decW_bf[i] = (__bf16)decW[i];
  for (size_t i = gid; i < 2048u; i += gsz) b_ar[i] = bih[i] + bhh[i];
  unsigned long long* hp = (unsigned long long*)h_all;
  for (size_t i = gid; i < 16384u; i += gsz) hp[i] = 0ULL;   // h slot 0 = zeros
  for (size_t i = gid; i < 512u; i += gsz) flags[i] = 0ULL;  // flag area 4KB
}

// ---------------------------------------------------------------------------
// setup1: Wfuse = Wih @ enc_W -> Wcat cols 512..575 ; b2 = bih+bhh+Wih@enc_b
// ---------------------------------------------------------------------------
__global__ void __launch_bounds__(64)
setup1(const float* __restrict__ Wih, const float* __restrict__ encW,
       const float* __restrict__ encb, const float* __restrict__ bih,
       const float* __restrict__ bhh, __bf16* __restrict__ Wcat,
       float* __restrict__ b2)
{
  int r = blockIdx.x;        // 0..2047
  int c = threadIdx.x;       // 0..63
  const float* wr = Wih + (size_t)r * 512;
  float acc = 0.f;
  for (int k = 0; k < 512; ++k) acc += wr[k] * encW[(size_t)k * 64 + c];
  Wcat[(size_t)r * 576 + 512 + c] = (__bf16)acc;
  float p = 0.f;
  for (int kk = 0; kk < 8; ++kk) { int k = kk * 64 + c; p += wr[k] * encb[k]; }
  for (int off = 32; off > 0; off >>= 1) p += __shfl_down(p, off);
  if (c == 0) b2[r] = bih[r] + bhh[r] + p;
}

// ---------------------------------------------------------------------------
// One LSTM step. block = 1024 thr (16 waves). MFMA wave wv: gate=wv&3,
// fsub=wv>>2. Gates + publish: tid<256 (waves 0..3), 8B piece per thread.
// ---------------------------------------------------------------------------
template<bool MAIN>
__device__ __forceinline__ void lstm_step(
    unsigned t, int tid, int wv, int lane, int b0, int f0,
    const bf16x8 (&wf)[18], float bv,
    __bf16* __restrict__ h_all, const __bf16* __restrict__ xT,
    f32x4& creg, __bf16 (*A)[584], float (*ex)[64][17],
    unsigned long long* __restrict__ flags, int g, int mysub)
{
  const int n16 = lane & 15, quad = lane >> 4;
  const int gate = wv & 3, fsub = wv >> 2;

  // ---- x prefetch (plain cached load; in flight during the flag wait) ----
  uint4 xv;
  if (MAIN && tid < 128)
    xv = *(const uint4*)(xT + (size_t)(t - 1) * 8192 +
                         (size_t)(b0 + (tid >> 3)) * 64 + (tid & 7) * 8);

  // ---- rendezvous: wait for my piece's producer to publish step t-1 ----
  if (t > 1) {
    const unsigned long long* fl =
        flags + (((size_t)g * 8 + (size_t)((tid & 63) >> 3)) << 3);
    while (__hip_atomic_load(fl, __ATOMIC_RELAXED, __HIP_MEMORY_SCOPE_AGENT)
           < (unsigned long long)(t - 1)) {}
  }

  // ---- data: 2 x 8B agent loads (MALL truth), issued exactly once ----
  const unsigned long long* src = (const unsigned long long*)
      (h_all + (size_t)(t - 1) * 65536 + (size_t)(b0 + (tid >> 6)) * 512) +
      (size_t)(tid & 63) * 2;
  unsigned long long v0 = __hip_atomic_load(src,     __ATOMIC_RELAXED, __HIP_MEMORY_SCOPE_AGENT);
  unsigned long long v1 = __hip_atomic_load(src + 1, __ATOMIC_RELAXED, __HIP_MEMORY_SCOPE_AGENT);

  // ---- stage A ----
  {
    unsigned long long* ad = (unsigned long long*)&A[tid >> 6][(tid & 63) * 8];
    ad[0] = v0; ad[1] = v1;
  }
  if (MAIN && tid < 128)
    *(uint4*)(&A[tid >> 3][512 + (tid & 7) * 8]) = xv;
  __syncthreads();

  // ---- MFMA: wave (gate, fsub); bias pre-loaded into accumulator ----
  if (MAIN || gate != 1) {
    f32x4 a0 = {bv, bv, bv, bv}, a1 = {0.f, 0.f, 0.f, 0.f};
    const __bf16* arow = &A[n16][quad * 8];
    #pragma unroll
    for (int kc = 0; kc < (MAIN ? 18 : 16); ++kc) {
      bf16x8 af = *(const bf16x8*)(arow + kc * 32);
      if (kc & 1) a1 = __builtin_amdgcn_mfma_f32_16x16x32_bf16(af, wf[kc], a1, 0, 0, 0);
      else        a0 = __builtin_amdgcn_mfma_f32_16x16x32_bf16(af, wf[kc], a0, 0, 0, 0);
    }
    a0 += a1;
    #pragma unroll
    for (int r = 0; r < 4; ++r)
      ex[gate][fsub * 16 + n16][quad * 4 + r] = a0[r];   // [gate][feat 0..63][batch]
  }
  __syncthreads();

  // ---- gates + publish: tid<256 (waves 0..3), one 8B piece each ----
  if (tid < 256) {
    const int em = tid >> 4, p = tid & 15;
    unsigned long long pk = 0;
    #pragma unroll
    for (int j = 0; j < 4; ++j) {
      const int ef = p * 4 + j;
      float ig = sigm(ex[0][ef][em]);
      float gg = tanh_fast(ex[2][ef][em]);
      float og = sigm(ex[3][ef][em]);
      float c2;
      if (MAIN) { float fg = sigm(ex[1][ef][em]); c2 = fg * creg[j] + ig * gg; creg[j] = c2; }
      else      { c2 = ig * gg; }               // AR: zero state
      float h2 = og * tanh_fast(c2);
      __bf16 hb = (__bf16)h2;
      pk |= (unsigned long long)__builtin_bit_cast(unsigned short, hb) << (16 * j);
    }
    unsigned long long* dst = (unsigned long long*)
        (h_all + (size_t)t * 65536 + (size_t)(b0 + em) * 512 + f0) + p;
    __hip_atomic_store(dst, pk, __ATOMIC_RELAXED, __HIP_MEMORY_SCOPE_AGENT);
    // all data-publishing waves (0..3) drain their stores to the MALL here,
    // BEFORE the barrier — flag=t therefore implies data is readable.
    asm volatile("s_waitcnt vmcnt(0)" ::: "memory");
  }
  __syncthreads();

  // ---- publish generation flag ----
  if (tid == 0)
    __hip_atomic_store(flags + (((size_t)g * 8 + (size_t)mysub) << 3),
                       (unsigned long long)t,
                       __ATOMIC_RELAXED, __HIP_MEMORY_SCOPE_AGENT);
}

__global__ void __launch_bounds__(1024, 4)
lstm_persist(const __bf16* __restrict__ xT, const __bf16* __restrict__ Wcat,
             const __bf16* __restrict__ Wih_bf, const float* __restrict__ b2,
             const float* __restrict__ b_ar, __bf16* __restrict__ h_all,
             unsigned long long* __restrict__ flags)
{
  const int bid = blockIdx.x;                  // 64 blocks
  const int g = bid & 7, sub = bid >> 3;       // group g (16 batches), 64 feats
  const int b0 = g * 16, f0 = sub * 64;
  const int tid = threadIdx.x;
  const int wv = tid >> 6, lane = tid & 63;
  const int n16 = lane & 15, quad = lane >> 4;
  const int gate = wv & 3, fsub = wv >> 2;

  __shared__ __align__(16) __bf16 A[16][584];  // 16 batch rows x (512 h + 64 x + pad)
  __shared__ float ex[4][64][17];              // gate exchange

  // persistent weight fragments (VGPR-resident): row = gate*512+f0+fsub*16+n16
  bf16x8 wf[18];
  {
    const __bf16* wrow = Wcat + (size_t)(gate * 512 + f0 + fsub * 16 + n16) * 576 + quad * 8;
    #pragma unroll
    for (int kc = 0; kc < 18; ++kc) wf[kc] = *(const bf16x8*)(wrow + kc * 32);
  }
  float bvm = b2[gate * 512 + f0 + fsub * 16 + n16];

  f32x4 creg = {0.f, 0.f, 0.f, 0.f};   // cell state c[b0+em][f0+p*4+j] (tid<256)

  for (unsigned t = 1; t <= 512; ++t)
    lstm_step<true>(t, tid, wv, lane, b0, f0, wf, bvm, h_all, xT, creg, A, ex,
                    flags, g, sub);

  { // AR phase: h feeds Wih with zero recurrent state
    const __bf16* wrow = Wih_bf + (size_t)(gate * 512 + f0 + fsub * 16 + n16) * 512 + quad * 8;
    #pragma unroll
    for (int kc = 0; kc < 16; ++kc) wf[kc] = *(const bf16x8*)(wrow + kc * 32);
  }
  float bva = b_ar[gate * 512 + f0 + fsub * 16 + n16];
  for (unsigned t = 513; t <= 704; ++t)
    lstm_step<false>(t, tid, wv, lane, b0, f0, wf, bva, h_all, xT, creg, A, ex,
                     flags, g, sub);
}

// ---------------------------------------------------------------------------
// final_proj: out[b][j][c] = h_slot[j+2][b][:] @ dec_W.T + dec_b, j=0..702.
// (lstm_persist kernel-end release flushes everything; cross-kernel visible.)
// ---------------------------------------------------------------------------
__global__ void __launch_bounds__(256)
final_proj(const __bf16* __restrict__ h_all, const __bf16* __restrict__ decW_bf,
           const float* __restrict__ decb, float* __restrict__ out)
{
  const int bi = blockIdx.x;               // 0..702
  const int tid = threadIdx.x;
  const int wv = tid >> 6, lane = tid & 63;
  const int n16 = lane & 15, quad = lane >> 4;
  const size_t r0 = 256 + (size_t)bi * 128 + (size_t)wv * 32;

  f32x4 acc[2][4];
  #pragma unroll
  for (int mt = 0; mt < 2; ++mt)
    #pragma unroll
    for (int nt = 0; nt < 4; ++nt) acc[mt][nt] = f32x4{0.f, 0.f, 0.f, 0.f};

  const __bf16* arow0 = h_all + (r0 + n16) * 512 + quad * 8;
  const __bf16* arow1 = arow0 + 16 * 512;
  const __bf16* brow  = decW_bf + (size_t)n16 * 512 + quad * 8;

  #pragma unroll
  for (int kc = 0; kc < 16; ++kc) {
    bf16x8 a0 = *(const bf16x8*)(arow0 + kc * 32);
    bf16x8 a1 = *(const bf16x8*)(arow1 + kc * 32);
    #pragma unroll
    for (int nt = 0; nt < 4; ++nt) {
      bf16x8 b = *(const bf16x8*)(brow + (size_t)nt * 8192 + kc * 32);
      acc[0][nt] = __builtin_amdgcn_mfma_f32_16x16x32_bf16(a0, b, acc[0][nt], 0, 0, 0);
      acc[1][nt] = __builtin_amdgcn_mfma_f32_16x16x32_bf16(a1, b, acc[1][nt], 0, 0, 0);
    }
  }
  #pragma unroll
  for (int mt = 0; mt < 2; ++mt)
    #pragma unroll
    for (int nt = 0; nt < 4; ++nt)
      #pragma unroll
      for (int r = 0; r < 4; ++r) {
        size_t R = r0 + mt * 16 + quad * 4 + r;      // h_all row
        int slot = (int)(R >> 7), b = (int)(R & 127);
        int j = slot - 2;
        int c = nt * 16 + n16;
        out[((size_t)b * 703 + j) * 64 + c] = acc[mt][nt][r] + decb[c];
      }
}

// ---------------------------------------------------------------------------
extern "C" void kernel_launch(void* const* d_in, const int* in_sizes, int n_in,
                              void* d_out, int out_size, void* d_ws, size_t ws_size,
                              hipStream_t stream)
{
  const float* x    = (const float*)d_in[0];
  const float* encW = (const float*)d_in[1];
  const float* encb = (const float*)d_in[2];
  const float* Wih  = (const float*)d_in[3];
  const float* Whh  = (const float*)d_in[4];
  const float* bih  = (const float*)d_in[5];
  const float* bhh  = (const float*)d_in[6];
  const float* decW = (const float*)d_in[7];
  const float* decb = (const float*)d_in[8];
  float* out = (float*)d_out;

  if (ws_size < WS_NEEDED) return;

  char* ws = (char*)d_ws;
  __bf16*             h_all   = (__bf16*)(ws + OFF_HALL);
  __bf16*             Wcat    = (__bf16*)(ws + OFF_WCAT);
  __bf16*             Wih_bf  = (__bf16*)(ws + OFF_WIH);
  __bf16*             decW_bf = (__bf16*)(ws + OFF_DECW);
  __bf16*             xT      = (__bf16*)(ws + OFF_XT);
  float*              b2      = (float*)(ws + OFF_B2);
  float*              b_ar    = (float*)(ws + OFF_BAR_);
  unsigned long long* flags   = (unsigned long long*)(ws + OFF_FLAG);

  hipLaunchKernelGGL(setup0, dim3(2048), dim3(256), 0, stream,
                     x, Wih, Whh, bih, bhh, decW, xT, Wih_bf, Wcat, decW_bf,
                     b_ar, h_all, flags);
  hipLaunchKernelGGL(setup1, dim3(2048), dim3(64), 0, stream,
                     Wih, encW, encb, bih, bhh, Wcat, b2);
  hipLaunchKernelGGL(lstm_persist, dim3(64), dim3(1024), 0, stream,
                     xT, Wcat, Wih_bf, b2, b_ar, h_all, flags);
  hipLaunchKernelGGL(final_proj, dim3(703), dim3(256), 0, stream,
                     h_all, decW_bf, decb, out);
}